// Round 5
// baseline (2463.696 us; speedup 1.0000x reference)
//
#include <hip/hip_runtime.h>
#include <stdint.h>

// Problem constants
#define PB 256
#define PT 64
#define PE 300
#define PH 512
#define PDA 350
#define PR 16
#define PS 64
#define PA 16

typedef __attribute__((ext_vector_type(8))) short short8;
typedef __attribute__((ext_vector_type(4))) float f4;
typedef __attribute__((ext_vector_type(4))) unsigned int u32x4;
typedef unsigned long long u64;

__device__ __forceinline__ float bf2f(unsigned short u) {
    unsigned v = ((unsigned)u) << 16;
    return __builtin_bit_cast(float, v);
}
__device__ __forceinline__ unsigned short f2bf(float f) {
    unsigned u = __builtin_bit_cast(unsigned int, f);
    u = u + 0x7fffu + ((u >> 16) & 1u);
    return (unsigned short)(u >> 16);
}
__device__ __forceinline__ float sigf(float x) { return 1.f / (1.f + __expf(-x)); }
__device__ __forceinline__ float tanhf_(float x) { return 1.f - 2.f / (1.f + __expf(2.f * x)); }

// ---------------- converters ----------------

__global__ __launch_bounds__(256) void k_embed(const int* __restrict__ tokens,
                                               const float* __restrict__ emb,
                                               unsigned short* __restrict__ X) {
    int idx = blockIdx.x * 256 + threadIdx.x;
    if (idx >= 16384 * 320) return;
    int row = idx / 320, e = idx - row * 320;
    int t = row >> 8, b = row & 255;
    float v = 0.f;
    if (e < 300) v = emb[(long)tokens[b * 64 + t] * 300 + e];
    X[idx] = f2bf(v);
}

__global__ __launch_bounds__(256) void k_cvt_pad(const float* __restrict__ src,
                                                 unsigned short* __restrict__ dst,
                                                 int N, int K, int N2, int K2) {
    int idx = blockIdx.x * 256 + threadIdx.x;
    if (idx >= N2 * K2) return;
    int n = idx / K2, k = idx - n * K2;
    float v = (n < N && k < K) ? src[(long)n * K + k] : 0.f;
    dst[idx] = f2bf(v);
}

__global__ __launch_bounds__(256) void k_capsT(const float* __restrict__ src,
                                               unsigned short* __restrict__ dst) {
    __shared__ float tile[32][33];
    int r = blockIdx.x, kb = blockIdx.y * 32, nb = blockIdx.z * 32;
    int tx = threadIdx.x & 31, ty = threadIdx.x >> 5;
    for (int i = 0; i < 32; i += 8)
        tile[ty + i][tx] = src[((long)r << 20) + (long)(kb + ty + i) * 1024 + nb + tx];
    __syncthreads();
    for (int i = 0; i < 32; i += 8)
        dst[((long)r << 20) + (long)(nb + ty + i) * 1024 + kb + tx] = f2bf(tile[tx][ty + i]);
}

__global__ __launch_bounds__(256) void k_whh_shuf(const float* __restrict__ W,
                                                  unsigned short* __restrict__ dst) {
    int idx = blockIdx.x * 256 + threadIdx.x;
    int el = idx & 7, lane = (idx >> 3) & 63, ks = (idx >> 9) & 15, nt = (idx >> 13) & 7, hs = idx >> 16;
    int gcol = (nt >> 1) * 512 + hs * 32 + (nt & 1) * 16 + (lane & 15);
    int k = ks * 32 + (lane >> 4) * 8 + el;
    dst[idx] = f2bf(W[(long)gcol * 512 + k]);
}

// ---------------- generic bf16 MFMA GEMM ----------------
template <int OUT_BF16, int TANH>
__global__ __launch_bounds__(256) void k_gemm(const unsigned short* __restrict__ A,
                                              const unsigned short* __restrict__ W,
                                              void* __restrict__ Cv,
                                              const float* __restrict__ bias,
                                              int K, int lda, int ldc,
                                              long aOffZ, long wOffZ, long cOffZ, long bOffZ) {
    A += blockIdx.z * aOffZ;
    W += blockIdx.z * wOffZ;
    if (bias) bias += blockIdx.z * bOffZ;
    const long cbase = blockIdx.z * cOffZ;
    const int m0 = blockIdx.x * 128, n0 = blockIdx.y * 128;
    __shared__ unsigned short As[4096], Bs[4096];
    const int w = threadIdx.x >> 6, l = threadIdx.x & 63;
    const int wm = w & 1, wn = w >> 1;
    const int fr = l & 15, fk = (l >> 4) * 8;
    f4 acc[4][4] = {};
    for (int k0 = 0; k0 < K; k0 += 32) {
        __syncthreads();
#pragma unroll
        for (int i = 0; i < 2; i++) {
            int tI = w + i * 4;
            const unsigned short* ga = A + (long)(m0 + tI * 16 + fr) * lda + k0 + fk;
            const unsigned short* gb = W + (long)(n0 + tI * 16 + fr) * K + k0 + fk;
            *(short8*)&As[tI * 512 + l * 8] = *(const short8*)ga;
            *(short8*)&Bs[tI * 512 + l * 8] = *(const short8*)gb;
        }
        __syncthreads();
        short8 av[4], bv[4];
#pragma unroll
        for (int mt = 0; mt < 4; mt++) av[mt] = *(short8*)&As[(wm * 4 + mt) * 512 + l * 8];
#pragma unroll
        for (int nt = 0; nt < 4; nt++) bv[nt] = *(short8*)&Bs[(wn * 4 + nt) * 512 + l * 8];
#pragma unroll
        for (int mt = 0; mt < 4; mt++)
#pragma unroll
            for (int nt = 0; nt < 4; nt++)
                acc[mt][nt] = __builtin_amdgcn_mfma_f32_16x16x32_bf16(av[mt], bv[nt], acc[mt][nt], 0, 0, 0);
    }
#pragma unroll
    for (int mt = 0; mt < 4; mt++) {
        int row = m0 + wm * 64 + mt * 16 + (l >> 4) * 4;
#pragma unroll
        for (int nt = 0; nt < 4; nt++) {
            int col = n0 + wn * 64 + nt * 16 + (l & 15);
            float bb = bias ? bias[col] : 0.f;
#pragma unroll
            for (int i = 0; i < 4; i++) {
                float v = acc[mt][nt][i] + bb;
                if (TANH) v = tanhf_(v);
                long off = cbase + (long)(row + i) * ldc + col;
                if (OUT_BF16)
                    ((unsigned short*)Cv)[off] = f2bf(v);
                else
                    ((float*)Cv)[off] = v;
            }
        }
    }
}

// ---------------- persistent bidirectional LSTM layer ----------------
// DATA-AS-SIGNAL protocol (placement-independent by construction):
//  * hsteps step buffers pre-filled with sentinel 0x7F7F (bf16 ~3.4e38;
//    h = sig*tanh in (-1,1) can never equal it; step-0 zeros neither).
//  * producers: per-element agent-scope relaxed stores. No drain/flag/counter.
//  * consumers: poll their own A-fragments with global_load_dwordx4 sc0 sc1
//    (bypass L1+L2 = read the device coherence point). Accept when no u16
//    equals the sentinel; write-once-per-step makes element-wise acceptance
//    sound under partial visibility, for ANY block->XCD placement.
//  * ROUND-4 BUG FIX (guide rule #18): the sentinel check is register-only
//    VALU work on the load destinations; hipcc may schedule it BETWEEN the
//    load asm and the `s_waitcnt vmcnt(0)` asm ("memory" clobber does not
//    order non-memory ops) -> check read stale registers (= previous step's
//    h), accepted, GEMM consumed step s-1 data (absmax 6.37). The fence is
//    __builtin_amdgcn_sched_barrier(0) IMMEDIATELY after the vmcnt(0).
//  * each wave polls only fragments IT consumes -> 64-step loop has NO
//    __syncthreads, NO flags, NO drains.
// Host re-memsets the sentinel between the two lstm dispatches (buffer reuse).
__global__ __launch_bounds__(256, 1) void k_lstm(const unsigned short* __restrict__ Zx,
                                                 const unsigned short* __restrict__ Wshuf,
                                                 unsigned short* __restrict__ hsteps,
                                                 unsigned short* __restrict__ Lout) {
    extern __shared__ char smem[];
    unsigned short* Wl = (unsigned short*)smem;        // 128 KB, resident all 64 steps
    const int bid = blockIdx.x;
    // XCD-colocating swizzle (locality hint only; protocol is placement-safe)
    const int g = bid & 7, hs = bid >> 3;
    const int dir = g >> 2, bg = g & 3;
    const int tid = threadIdx.x;
    const int l = tid & 63;
    const int w = tid >> 6;
    const int mt2 = w & 1, hc2 = w >> 1;

    // Whh slice into LDS (resident for all 64 steps)
    {
        const short8* src = (const short8*)(Wshuf + ((long)(dir * 16 + hs) << 16));
        short8* dst = (short8*)Wl;
        for (int i = tid; i < 8192; i += 256) dst[i] = src[i];
    }
    // step-0 h = 0 (agent-scope; zeros are the "data ready" signal)
    {
        unsigned short* hz = hsteps + (long)dir * (256 * 512);
        for (int i = tid; i < 1024; i += 256) {
            int r = i >> 4, c2 = i & 15;
            __hip_atomic_store((unsigned*)&hz[(bg * 64 + r) * 512 + hs * 32 + c2 * 2], 0u,
                               __ATOMIC_RELAXED, __HIP_MEMORY_SCOPE_AGENT);
        }
    }
    __syncthreads();  // Wl ready; h stores are in flight (consumers poll)

    float c_reg[8];
#pragma unroll
    for (int i = 0; i < 8; i++) c_reg[i] = 0.f;

    // this lane's fixed output cells: rows rbase+i2*16+i, col colg
    const int colg = hs * 32 + hc2 * 16 + (l & 15);
    const int rbase = bg * 64 + mt2 * 32 + (l >> 4) * 4;

    // Zx gate prefetch one step ahead (HBM latency hides under poll+GEMM)
    unsigned short zpre[2][4][4];
    auto zfetch = [&](int t_eff) {
        const unsigned short* zbase = Zx + ((long)dir * 16384 + (long)t_eff * 256) * 2048;
#pragma unroll
        for (int i2 = 0; i2 < 2; i2++)
#pragma unroll
            for (int i = 0; i < 4; i++) {
                const unsigned short* zrow = zbase + (long)(rbase + i2 * 16 + i) * 2048 + colg;
#pragma unroll
                for (int s = 0; s < 4; s++) zpre[i2][i][s] = zrow[s * 512];
            }
    };
    zfetch(dir ? 63 : 0);

    for (int step = 0; step < 64; step++) {
        const int t_eff = dir ? (63 - step) : step;

        // ---- poll this wave's A-fragments until sentinel-free ----
        const unsigned short* hbp = hsteps + ((long)step * 2 + dir) * (256 * 512);
        const unsigned short* pa0 = hbp + (bg * 64 + (mt2 * 2 + 0) * 16 + (l & 15)) * 512 + (l >> 4) * 8;
        const unsigned short* pa1 = hbp + (bg * 64 + (mt2 * 2 + 1) * 16 + (l & 15)) * 512 + (l >> 4) * 8;
        u32x4 a0u[16], a1u[16];
        int dirty;
        do {
#pragma unroll
            for (int ks = 0; ks < 16; ks++) {
                asm volatile("global_load_dwordx4 %0, %1, off offset:%2 sc0 sc1"
                             : "=v"(a0u[ks]) : "v"(pa0), "i"(ks * 64));
                asm volatile("global_load_dwordx4 %0, %1, off offset:%2 sc0 sc1"
                             : "=v"(a1u[ks]) : "v"(pa1), "i"(ks * 64));
            }
            asm volatile("s_waitcnt vmcnt(0)" ::: "memory");
            // HARD scheduler fence: nothing (incl. the register-only sentinel
            // checks below and the MFMAs) may be scheduled above this point.
            __builtin_amdgcn_sched_barrier(0);
            dirty = 0;
#pragma unroll
            for (int ks = 0; ks < 16; ks++)
#pragma unroll
                for (int j = 0; j < 4; j++) {
                    unsigned x0 = a0u[ks][j], x1 = a1u[ks][j];
                    dirty |= ((x0 & 0xFFFFu) == 0x7F7Fu) | ((x0 >> 16) == 0x7F7Fu);
                    dirty |= ((x1 & 0xFFFFu) == 0x7F7Fu) | ((x1 >> 16) == 0x7F7Fu);
                }
        } while (__ballot(dirty) != 0ULL);

        // ---- GEMM: h @ WhhT(slice) ----
        f4 acc[2][4] = {};
#pragma unroll
        for (int ks = 0; ks < 16; ks++) {
            short8 a0 = __builtin_bit_cast(short8, a0u[ks]);
            short8 a1 = __builtin_bit_cast(short8, a1u[ks]);
#pragma unroll
            for (int s = 0; s < 4; s++) {
                int nt = s * 2 + hc2;
                short8 b = *(short8*)&Wl[((nt * 16 + ks) * 64 + l) * 8];
                acc[0][s] = __builtin_amdgcn_mfma_f32_16x16x32_bf16(a0, b, acc[0][s], 0, 0, 0);
                acc[1][s] = __builtin_amdgcn_mfma_f32_16x16x32_bf16(a1, b, acc[1][s], 0, 0, 0);
            }
        }

        // ---- in-lane gate math; h stores ARE the next-step signal ----
        unsigned short* hw = hsteps + ((long)(step + 1) * 2 + dir) * (256 * 512);
        unsigned short hv[2][4];
#pragma unroll
        for (int i2 = 0; i2 < 2; i2++)
#pragma unroll
            for (int i = 0; i < 4; i++) {
                float zi = acc[i2][0][i] + bf2f(zpre[i2][i][0]);
                float zf = acc[i2][1][i] + bf2f(zpre[i2][i][1]);
                float zg = acc[i2][2][i] + bf2f(zpre[i2][i][2]);
                float zo = acc[i2][3][i] + bf2f(zpre[i2][i][3]);
                int ci = i2 * 4 + i;
                float cc = sigf(zf) * c_reg[ci] + sigf(zi) * tanhf_(zg);
                c_reg[ci] = cc;
                float hh = sigf(zo) * tanhf_(cc);
                unsigned short h16 = f2bf(hh);
                hv[i2][i] = h16;
                __hip_atomic_store(&hw[(long)(rbase + i2 * 16 + i) * 512 + colg], h16,
                                   __ATOMIC_RELAXED, __HIP_MEMORY_SCOPE_AGENT);
            }
        // next step's Zx prefetch + Lout stores: fire-and-forget (the next
        // poll's vmcnt(0) self-paces; no barrier, no drain, no signal).
        if (step < 63) zfetch(dir ? (62 - step) : (step + 1));
#pragma unroll
        for (int i2 = 0; i2 < 2; i2++)
#pragma unroll
            for (int i = 0; i < 4; i++)
                Lout[((long)t_eff * 256 + rbase + i2 * 16 + i) * 1024 + dir * 512 + colg] = hv[i2][i];
    }
}

// ---------------- alphas ----------------
__global__ __launch_bounds__(256) void k_alphas(const unsigned short* __restrict__ hbar,
                                                const unsigned short* __restrict__ ws2,
                                                float* __restrict__ att) {
    int w = threadIdx.x >> 6, l = threadIdx.x & 63;
    int mtile = blockIdx.x * 4 + w;
    f4 acc = {};
    const unsigned short* arow = hbar + (long)(mtile * 16 + (l & 15)) * 384 + (l >> 4) * 8;
    const unsigned short* brow = ws2 + (long)(l & 15) * 384 + (l >> 4) * 8;
    for (int ks = 0; ks < 12; ks++) {
        short8 a = *(const short8*)&arow[ks * 32];
        short8 b = *(const short8*)&brow[ks * 32];
        acc = __builtin_amdgcn_mfma_f32_16x16x32_bf16(a, b, acc, 0, 0, 0);
    }
    int r = l & 15;
#pragma unroll
    for (int i = 0; i < 4; i++) {
        int bt = mtile * 16 + (l >> 4) * 4 + i;
        int b = bt & 255, t = bt >> 8;
        att[((long)b * 16 + r) * 64 + t] = acc[i];
    }
}

// ---------------- sent: each thread owns one n-col, 8 r-accumulators ----------------
__global__ __launch_bounds__(256) void k_sent(const float* __restrict__ att,
                                              const unsigned short* __restrict__ L1,
                                              float* __restrict__ sent,
                                              unsigned short* __restrict__ sentb) {
    int b = blockIdx.x, n0 = blockIdx.y * 128;
    __shared__ float al[1024];
    for (int i = threadIdx.x; i < 1024; i += 256) al[i] = att[(long)b * 1024 + i];
    __syncthreads();
    int n = n0 + (threadIdx.x & 127);
    int rh = (threadIdx.x >> 7) * 8;
    float acc[8] = {};
    for (int t = 0; t < 64; t++) {
        float x = bf2f(L1[((long)t * 256 + b) * 1024 + n]);
#pragma unroll
        for (int r = 0; r < 8; r++) acc[r] += al[(rh + r) * 64 + t] * x;
    }
#pragma unroll
    for (int r = 0; r < 8; r++) {
        long o = ((long)b * 16 + rh + r) * 1024 + n;
        sent[o] = acc[r];
        sentb[o] = f2bf(acc[r]);
    }
}

// ---------------- dynamic routing ----------------
__global__ __launch_bounds__(256) void k_route(const float* __restrict__ votes,
                                               float* __restrict__ clog) {
    __shared__ float v[16384];
    __shared__ float logits[1024];
    __shared__ float route[1024];
    __shared__ float pre[1024];
    __shared__ float act[1024];
    __shared__ float cl[64];
    int b = blockIdx.x, tid = threadIdx.x;
    for (int i = tid; i < 4096; i += 256) ((f4*)v)[i] = ((const f4*)(votes + (long)b * 16384))[i];
    for (int i = tid; i < 1024; i += 256) logits[i] = 0.f;
    __syncthreads();
    for (int it = 0; it < 3; it++) {
        if (tid < 16) {
            float m = -1e30f;
            for (int s = 0; s < 64; s++) m = fmaxf(m, logits[tid * 64 + s]);
            float sum = 0.f;
            for (int s = 0; s < 64; s++) {
                float e = __expf(logits[tid * 64 + s] - m);
                route[tid * 64 + s] = e;
                sum += e;
            }
            float inv = 1.f / sum;
            for (int s = 0; s < 64; s++) route[tid * 64 + s] *= inv;
        }
        __syncthreads();
#pragma unroll
        for (int k = 0; k < 4; k++) {
            int p = k * 256 + tid;
            int s = p >> 4, a = p & 15;
            float acc = 0.f;
            for (int r = 0; r < 16; r++) acc += route[r * 64 + s] * v[(r * 64 + s) * 16 + a];
            pre[p] = acc;
        }
        __syncthreads();
        if (tid < 64) {
            float nsq = 0.f;
            for (int a = 0; a < 16; a++) nsq += pre[tid * 16 + a] * pre[tid * 16 + a];
            float norm = sqrtf(nsq);
            float sc = norm / (0.5f + nsq);
            for (int a = 0; a < 16; a++) act[tid * 16 + a] = pre[tid * 16 + a] * sc;
            cl[tid] = nsq / (0.5f + nsq);
        }
        __syncthreads();
#pragma unroll
        for (int k = 0; k < 4; k++) {
            int p = k * 256 + tid;
            int r = p >> 6, s = p & 63;
            float acc = 0.f;
            for (int a = 0; a < 16; a++) acc += v[(r * 64 + s) * 16 + a] * act[s * 16 + a];
            logits[p] += acc;
        }
        __syncthreads();
    }
    if (tid < 64) clog[(long)b * 64 + tid] = cl[tid];
}

// ---------------- host ----------------
extern "C" void kernel_launch(void* const* d_in, const int* in_sizes, int n_in,
                              void* d_out, int out_size, void* d_ws, size_t ws_size,
                              hipStream_t stream) {
    const int* tokens = (const int*)d_in[0];
    const float* embedding = (const float*)d_in[2];
    const float* Wih_l0f = (const float*)d_in[3];
    const float* Whh_l0f = (const float*)d_in[4];
    const float* b_l0f = (const float*)d_in[5];
    const float* Wih_l0b = (const float*)d_in[6];
    const float* Whh_l0b = (const float*)d_in[7];
    const float* b_l0b = (const float*)d_in[8];
    const float* Wih_l1f = (const float*)d_in[9];
    const float* Whh_l1f = (const float*)d_in[10];
    const float* b_l1f = (const float*)d_in[11];
    const float* Wih_l1b = (const float*)d_in[12];
    const float* Whh_l1b = (const float*)d_in[13];
    const float* b_l1b = (const float*)d_in[14];
    const float* ws1 = (const float*)d_in[15];
    const float* ws2 = (const float*)d_in[16];
    const float* caps_W = (const float*)d_in[17];
    float* out = (float*)d_out;

    char* ws = (char*)d_ws;
    size_t o = 0;
    unsigned short* Xb16 = (unsigned short*)(ws + o); o += (size_t)16384 * 320 * 2;
    unsigned short* ZxL = (unsigned short*)(ws + o); size_t zx_off = o; o += (size_t)2 * 16384 * 2048 * 2;
    unsigned short* L0 = (unsigned short*)(ws + o); o += (size_t)16384 * 1024 * 2;
    unsigned short* L1 = (unsigned short*)(ws + o); o += (size_t)16384 * 1024 * 2;
    unsigned short* Wl0b = (unsigned short*)(ws + o); o += (size_t)2 * 2048 * 320 * 2;
    unsigned short* Wl1b = (unsigned short*)(ws + o); o += (size_t)2 * 2048 * 1024 * 2;
    unsigned short* Wsh0 = (unsigned short*)(ws + o); o += (size_t)2 * 1048576 * 2;
    unsigned short* Wsh1 = (unsigned short*)(ws + o); o += (size_t)2 * 1048576 * 2;
    unsigned short* ws1b = (unsigned short*)(ws + o); o += (size_t)384 * 1024 * 2;
    unsigned short* ws2b = (unsigned short*)(ws + o); o += (size_t)16 * 384 * 2 + 192;
    float* biasc = (float*)(ws + o); o += (size_t)4 * 2048 * 4;
    // UNION region: hsteps (34.1 MB, live only during the two k_lstm dispatches)
    // and capsT (33.5 MB, written after layer-1 lstm, read by the votes GEMM).
    const size_t HS_BYTES = (size_t)65 * 2 * 256 * 512 * 2;
    unsigned short* hsteps = (unsigned short*)(ws + o);
    unsigned short* capsT = (unsigned short*)(ws + o);
    o += HS_BYTES;
    // overlay region (inside ZxL, dead after layer-1 recurrence):
    unsigned short* hbarb = (unsigned short*)(ws + zx_off);
    float* att = (float*)(ws + zx_off + (size_t)16384 * 384 * 2);
    unsigned short* sentb = (unsigned short*)(ws + zx_off + (size_t)16384 * 384 * 2 + 1048576);
    float* votes = (float*)(ws + zx_off + (size_t)16384 * 384 * 2 + 1048576 + (size_t)256 * 16 * 1024 * 2);

    // sentinel-fill for layer-0 lstm (0x7F7F bf16 ~ 3.4e38, impossible h)
    hipMemsetAsync(hsteps, 0x7F, HS_BYTES, stream);

    k_embed<<<16384 * 320 / 256, 256, 0, stream>>>(tokens, embedding, Xb16);
    k_cvt_pad<<<(2048 * 320 + 255) / 256, 256, 0, stream>>>(Wih_l0f, Wl0b, 2048, 300, 2048, 320);
    k_cvt_pad<<<(2048 * 320 + 255) / 256, 256, 0, stream>>>(Wih_l0b, Wl0b + (size_t)2048 * 320, 2048, 300, 2048, 320);
    k_cvt_pad<<<(2048 * 1024 + 255) / 256, 256, 0, stream>>>(Wih_l1f, Wl1b, 2048, 1024, 2048, 1024);
    k_cvt_pad<<<(2048 * 1024 + 255) / 256, 256, 0, stream>>>(Wih_l1b, Wl1b + (size_t)2048 * 1024, 2048, 1024, 2048, 1024);
    k_cvt_pad<<<(384 * 1024 + 255) / 256, 256, 0, stream>>>(ws1, ws1b, 350, 1024, 384, 1024);
    k_cvt_pad<<<(16 * 384 + 255) / 256, 256, 0, stream>>>(ws2, ws2b, 16, 350, 16, 384);
    k_whh_shuf<<<4096, 256, 0, stream>>>(Whh_l0f, Wsh0);
    k_whh_shuf<<<4096, 256, 0, stream>>>(Whh_l0b, Wsh0 + 1048576);
    k_whh_shuf<<<4096, 256, 0, stream>>>(Whh_l1f, Wsh1);
    k_whh_shuf<<<4096, 256, 0, stream>>>(Whh_l1b, Wsh1 + 1048576);
    hipMemcpyAsync(biasc + 0, b_l0f, 2048 * 4, hipMemcpyDeviceToDevice, stream);
    hipMemcpyAsync(biasc + 2048, b_l0b, 2048 * 4, hipMemcpyDeviceToDevice, stream);
    hipMemcpyAsync(biasc + 4096, b_l1f, 2048 * 4, hipMemcpyDeviceToDevice, stream);
    hipMemcpyAsync(biasc + 6144, b_l1b, 2048 * 4, hipMemcpyDeviceToDevice, stream);

    hipFuncSetAttribute(reinterpret_cast<const void*>(k_lstm),
                        hipFuncAttributeMaxDynamicSharedMemorySize, 131072);

    k_gemm<1, 0><<<dim3(128, 16, 2), 256, 0, stream>>>(
        Xb16, Wl0b, ZxL, biasc, 320, 320, 2048,
        0L, (long)2048 * 320, (long)16384 * 2048, 2048L);
    k_lstm<<<128, 256, 131072, stream>>>(ZxL, Wsh0, hsteps, L0);
    // re-arm sentinel for layer-1 lstm (buffer reuse; stream-ordered)
    hipMemsetAsync(hsteps, 0x7F, HS_BYTES, stream);
    k_gemm<1, 0><<<dim3(128, 16, 2), 256, 0, stream>>>(
        L0, Wl1b, ZxL, biasc + 4096, 1024, 1024, 2048,
        0L, (long)2048 * 1024, (long)16384 * 2048, 2048L);
    k_lstm<<<128, 256, 131072, stream>>>(ZxL, Wsh1, hsteps, L1);
    // capsT conversion AFTER the lstms: its buffer aliases hsteps (dead now)
    k_capsT<<<dim3(16, 32, 32), 256, 0, stream>>>(caps_W, capsT);
    k_gemm<1, 1><<<dim3(128, 3, 1), 256, 0, stream>>>(
        L1, ws1b, hbarb, nullptr, 1024, 1024, 384, 0L, 0L, 0L, 0L);
    k_alphas<<<256, 256, 0, stream>>>(hbarb, ws2b, att);
    k_sent<<<dim3(256, 8), 256, 0, stream>>>(att, L1, out, sentb);
    k_gemm<0, 0><<<dim3(2, 8, 16), 256, 0, stream>>>(
        sentb, capsT, votes, nullptr, 1024, 16384, 16384,
        1024L, 1048576L, 1024L, 0L);
    k_route<<<256, 256, 0, stream>>>(votes, out + (size_t)4194304);
}

// Round 9
// 1901.485 us; speedup vs baseline: 1.2957x; 1.2957x over previous
//
#include <hip/hip_runtime.h>
#include <stdint.h>

// Problem constants
#define PB 256
#define PT 64
#define PE 300
#define PH 512
#define PDA 350
#define PR 16
#define PS 64
#define PA 16

typedef __attribute__((ext_vector_type(8))) short short8;
typedef __attribute__((ext_vector_type(4))) float f4;
typedef __attribute__((ext_vector_type(4))) unsigned int u32x4;
typedef unsigned long long u64;

__device__ __forceinline__ float bf2f(unsigned short u) {
    unsigned v = ((unsigned)u) << 16;
    return __builtin_bit_cast(float, v);
}
__device__ __forceinline__ unsigned short f2bf(float f) {
    unsigned u = __builtin_bit_cast(unsigned int, f);
    u = u + 0x7fffu + ((u >> 16) & 1u);
    return (unsigned short)(u >> 16);
}
__device__ __forceinline__ float sigf(float x) { return 1.f / (1.f + __expf(-x)); }
__device__ __forceinline__ float tanhf_(float x) { return 1.f - 2.f / (1.f + __expf(2.f * x)); }

// ---------------- converters ----------------

__global__ __launch_bounds__(256) void k_embed(const int* __restrict__ tokens,
                                               const float* __restrict__ emb,
                                               unsigned short* __restrict__ X) {
    int idx = blockIdx.x * 256 + threadIdx.x;
    if (idx >= 16384 * 320) return;
    int row = idx / 320, e = idx - row * 320;
    int t = row >> 8, b = row & 255;
    float v = 0.f;
    if (e < 300) v = emb[(long)tokens[b * 64 + t] * 300 + e];
    X[idx] = f2bf(v);
}

__global__ __launch_bounds__(256) void k_cvt_pad(const float* __restrict__ src,
                                                 unsigned short* __restrict__ dst,
                                                 int N, int K, int N2, int K2) {
    int idx = blockIdx.x * 256 + threadIdx.x;
    if (idx >= N2 * K2) return;
    int n = idx / K2, k = idx - n * K2;
    float v = (n < N && k < K) ? src[(long)n * K + k] : 0.f;
    dst[idx] = f2bf(v);
}

__global__ __launch_bounds__(256) void k_capsT(const float* __restrict__ src,
                                               unsigned short* __restrict__ dst) {
    __shared__ float tile[32][33];
    int r = blockIdx.x, kb = blockIdx.y * 32, nb = blockIdx.z * 32;
    int tx = threadIdx.x & 31, ty = threadIdx.x >> 5;
    for (int i = 0; i < 32; i += 8)
        tile[ty + i][tx] = src[((long)r << 20) + (long)(kb + ty + i) * 1024 + nb + tx];
    __syncthreads();
    for (int i = 0; i < 32; i += 8)
        dst[((long)r << 20) + (long)(nb + ty + i) * 1024 + kb + tx] = f2bf(tile[tx][ty + i]);
}

__global__ __launch_bounds__(256) void k_whh_shuf(const float* __restrict__ W,
                                                  unsigned short* __restrict__ dst) {
    int idx = blockIdx.x * 256 + threadIdx.x;
    int el = idx & 7, lane = (idx >> 3) & 63, ks = (idx >> 9) & 15, nt = (idx >> 13) & 7, hs = idx >> 16;
    int gcol = (nt >> 1) * 512 + hs * 32 + (nt & 1) * 16 + (lane & 15);
    int k = ks * 32 + (lane >> 4) * 8 + el;
    dst[idx] = f2bf(W[(long)gcol * 512 + k]);
}

// ---------------- generic bf16 MFMA GEMM ----------------
template <int OUT_BF16, int TANH>
__global__ __launch_bounds__(256) void k_gemm(const unsigned short* __restrict__ A,
                                              const unsigned short* __restrict__ W,
                                              void* __restrict__ Cv,
                                              const float* __restrict__ bias,
                                              int K, int lda, int ldc,
                                              long aOffZ, long wOffZ, long cOffZ, long bOffZ) {
    A += blockIdx.z * aOffZ;
    W += blockIdx.z * wOffZ;
    if (bias) bias += blockIdx.z * bOffZ;
    const long cbase = blockIdx.z * cOffZ;
    const int m0 = blockIdx.x * 128, n0 = blockIdx.y * 128;
    __shared__ unsigned short As[4096], Bs[4096];
    const int w = threadIdx.x >> 6, l = threadIdx.x & 63;
    const int wm = w & 1, wn = w >> 1;
    const int fr = l & 15, fk = (l >> 4) * 8;
    f4 acc[4][4] = {};
    for (int k0 = 0; k0 < K; k0 += 32) {
        __syncthreads();
#pragma unroll
        for (int i = 0; i < 2; i++) {
            int tI = w + i * 4;
            const unsigned short* ga = A + (long)(m0 + tI * 16 + fr) * lda + k0 + fk;
            const unsigned short* gb = W + (long)(n0 + tI * 16 + fr) * K + k0 + fk;
            *(short8*)&As[tI * 512 + l * 8] = *(const short8*)ga;
            *(short8*)&Bs[tI * 512 + l * 8] = *(const short8*)gb;
        }
        __syncthreads();
        short8 av[4], bv[4];
#pragma unroll
        for (int mt = 0; mt < 4; mt++) av[mt] = *(short8*)&As[(wm * 4 + mt) * 512 + l * 8];
#pragma unroll
        for (int nt = 0; nt < 4; nt++) bv[nt] = *(short8*)&Bs[(wn * 4 + nt) * 512 + l * 8];
#pragma unroll
        for (int mt = 0; mt < 4; mt++)
#pragma unroll
            for (int nt = 0; nt < 4; nt++)
                acc[mt][nt] = __builtin_amdgcn_mfma_f32_16x16x32_bf16(av[mt], bv[nt], acc[mt][nt], 0, 0, 0);
    }
#pragma unroll
    for (int mt = 0; mt < 4; mt++) {
        int row = m0 + wm * 64 + mt * 16 + (l >> 4) * 4;
#pragma unroll
        for (int nt = 0; nt < 4; nt++) {
            int col = n0 + wn * 64 + nt * 16 + (l & 15);
            float bb = bias ? bias[col] : 0.f;
#pragma unroll
            for (int i = 0; i < 4; i++) {
                float v = acc[mt][nt][i] + bb;
                if (TANH) v = tanhf_(v);
                long off = cbase + (long)(row + i) * ldc + col;
                if (OUT_BF16)
                    ((unsigned short*)Cv)[off] = f2bf(v);
                else
                    ((float*)Cv)[off] = v;
            }
        }
    }
}

// ---------------- persistent bidirectional LSTM layer ----------------
// HYBRID protocol: per-wave flags for the cheap WAIT + sentinel-verified
// sc0sc1 reads for the authoritative DATA (each piece separately HW-proven).
//
//  R8 post-mortem: flags alone + CACHED h reads gave absmax 7.8e-05 — the
//  producer's vmcnt(0)-acked sc1 h-stores and the subsequent flag store take
//  ADDRESS-INTERLEAVED IF channels with no cross-channel ordering, so the
//  flag can land at the coherence point ns before the h data. R2 masked this
//  with ~us of barrier+counter latency; R5 (data-as-signal, sc0sc1 reads)
//  was immune by per-address ordering and PASSED — but burned IF bandwidth
//  re-reading 32KB per retry while waiting (895us).
//
//  Here: consumers (1) poll the 32 producer flags (advisory, removes the
//  retry storm), then (2) read h via global_load_dwordx4 sc0 sc1 and verify
//  no u16 equals the 0x7F7F sentinel (authoritative, per-address-ordered,
//  exactly R5's proven mechanism); retry only in the ns flag-vs-data window.
//  hsteps is sentinel-filled by the host before each lstm dispatch; h in
//  (-1,1) and the step-0 zeros can never equal 0x7F7F.
//  Producer: h stores (agent relaxed u16) -> vmcnt(0) -> lane0 flag store.
//  NO __syncthreads in the 64-step loop. 65 step buffers -> no WAR.
//  Flags: monotonic u32 at cnt[((g*2+mt2)*32+hs*2+hc2)*32], 128-B spaced;
//  one layer region = 16384 u32 = 64 KiB (layer-1 base = cnt+16384; the
//  R6/R7 hang was +32768 aliasing hsteps).
__global__ __launch_bounds__(256, 1) void k_lstm(const unsigned short* __restrict__ Zx,
                                                 const unsigned short* __restrict__ Wshuf,
                                                 unsigned short* __restrict__ hsteps,
                                                 unsigned short* __restrict__ Lout,
                                                 unsigned* __restrict__ cnt) {
    extern __shared__ char smem[];
    unsigned short* Wl = (unsigned short*)smem;        // 128 KB, resident all 64 steps
    const int bid = blockIdx.x;
    // XCD-colocating swizzle (locality hint; protocol is placement-safe)
    const int g = bid & 7, hs = bid >> 3;
    const int dir = g >> 2, bg = g & 3;
    const int tid = threadIdx.x;
    const int l = tid & 63;
    const int w = tid >> 6;
    const int mt2 = w & 1, hc2 = w >> 1;

    // Whh slice into LDS (resident for all 64 steps)
    {
        const short8* src = (const short8*)(Wshuf + ((long)(dir * 16 + hs) << 16));
        short8* dst = (short8*)Wl;
        for (int i = tid; i < 8192; i += 256) dst[i] = src[i];
    }

    // this lane's fixed output cells: rows rbase+i2*16+i, col colg
    const int colg = hs * 32 + hc2 * 16 + (l & 15);
    const int rbase = bg * 64 + mt2 * 32 + (l >> 4) * 4;

    unsigned* fme = cnt + (size_t)(((g * 2 + mt2) * 32) + hs * 2 + hc2) * 32;  // my flag
    unsigned* fb = cnt + (size_t)((g * 2 + mt2) * 32) * 32;                    // flags I wait on

    // prologue: zero MY wave's step-0 cells (agent), drain, signal flag=1
    {
        unsigned short* hz = hsteps + (long)dir * (256 * 512);
#pragma unroll
        for (int i2 = 0; i2 < 2; i2++)
#pragma unroll
            for (int i = 0; i < 4; i++)
                __hip_atomic_store(&hz[(long)(rbase + i2 * 16 + i) * 512 + colg], (unsigned short)0,
                                   __ATOMIC_RELAXED, __HIP_MEMORY_SCOPE_AGENT);
    }
    asm volatile("s_waitcnt vmcnt(0)" ::: "memory");
    if (l == 0) __hip_atomic_store(fme, 1u, __ATOMIC_RELAXED, __HIP_MEMORY_SCOPE_AGENT);
    __syncthreads();  // Wl ready (only barrier in the kernel)

    float c_reg[8];
#pragma unroll
    for (int i = 0; i < 8; i++) c_reg[i] = 0.f;

    // Zx gate prefetch one step ahead (HBM latency hides under poll+GEMM)
    unsigned short zpre[2][4][4];
    auto zfetch = [&](int t_eff) {
        const unsigned short* zbase = Zx + ((long)dir * 16384 + (long)t_eff * 256) * 2048;
#pragma unroll
        for (int i2 = 0; i2 < 2; i2++)
#pragma unroll
            for (int i = 0; i < 4; i++) {
                const unsigned short* zrow = zbase + (long)(rbase + i2 * 16 + i) * 2048 + colg;
#pragma unroll
                for (int s = 0; s < 4; s++) zpre[i2][i][s] = zrow[s * 512];
            }
    };
    zfetch(dir ? 63 : 0);

    for (int step = 0; step < 64; step++) {
        const int t_eff = dir ? (63 - step) : step;
        const unsigned target = (unsigned)(step + 1);

        // ---- (1) advisory wait: poll the 32 producer flags (lanes 0..31) ----
        unsigned v;
        do {
            v = target;
            if (l < 32)
                v = __hip_atomic_load(fb + (size_t)l * 32, __ATOMIC_RELAXED, __HIP_MEMORY_SCOPE_AGENT);
        } while (__ballot(v < target) != 0ULL);

        // ---- (2) authoritative read: sc0sc1 loads + sentinel verify ----
        const unsigned short* hbp = hsteps + ((long)step * 2 + dir) * (256 * 512);
        const unsigned short* pa0 = hbp + (bg * 64 + (mt2 * 2 + 0) * 16 + (l & 15)) * 512 + (l >> 4) * 8;
        const unsigned short* pa1 = hbp + (bg * 64 + (mt2 * 2 + 1) * 16 + (l & 15)) * 512 + (l >> 4) * 8;
        u32x4 a0u[16], a1u[16];
        int dirty;
        do {
#pragma unroll
            for (int ks = 0; ks < 16; ks++) {
                asm volatile("global_load_dwordx4 %0, %1, off offset:%2 sc0 sc1"
                             : "=v"(a0u[ks]) : "v"(pa0), "i"(ks * 64));
                asm volatile("global_load_dwordx4 %0, %1, off offset:%2 sc0 sc1"
                             : "=v"(a1u[ks]) : "v"(pa1), "i"(ks * 64));
            }
            asm volatile("s_waitcnt vmcnt(0)" ::: "memory");
            __builtin_amdgcn_sched_barrier(0);  // rule #18: nothing above this line
            dirty = 0;
#pragma unroll
            for (int ks = 0; ks < 16; ks++)
#pragma unroll
                for (int j = 0; j < 4; j++) {
                    unsigned x0 = a0u[ks][j], x1 = a1u[ks][j];
                    dirty |= ((x0 & 0xFFFFu) == 0x7F7Fu) | ((x0 >> 16) == 0x7F7Fu);
                    dirty |= ((x1 & 0xFFFFu) == 0x7F7Fu) | ((x1 >> 16) == 0x7F7Fu);
                }
        } while (__ballot(dirty) != 0ULL);  // ~always 0 retries (flags passed)

        // ---- GEMM: h @ WhhT(slice) ----
        f4 acc[2][4] = {};
#pragma unroll
        for (int ks = 0; ks < 16; ks++) {
            short8 a0 = __builtin_bit_cast(short8, a0u[ks]);
            short8 a1 = __builtin_bit_cast(short8, a1u[ks]);
#pragma unroll
            for (int s = 0; s < 4; s++) {
                int nt = s * 2 + hc2;
                short8 b = *(short8*)&Wl[((nt * 16 + ks) * 64 + l) * 8];
                acc[0][s] = __builtin_amdgcn_mfma_f32_16x16x32_bf16(a0, b, acc[0][s], 0, 0, 0);
                acc[1][s] = __builtin_amdgcn_mfma_f32_16x16x32_bf16(a1, b, acc[1][s], 0, 0, 0);
            }
        }

        // ---- in-lane gate math; store h; drain; signal my flag ----
        unsigned short* hw = hsteps + ((long)(step + 1) * 2 + dir) * (256 * 512);
        unsigned short hv[2][4];
#pragma unroll
        for (int i2 = 0; i2 < 2; i2++)
#pragma unroll
            for (int i = 0; i < 4; i++) {
                float zi = acc[i2][0][i] + bf2f(zpre[i2][i][0]);
                float zf = acc[i2][1][i] + bf2f(zpre[i2][i][1]);
                float zg = acc[i2][2][i] + bf2f(zpre[i2][i][2]);
                float zo = acc[i2][3][i] + bf2f(zpre[i2][i][3]);
                int ci = i2 * 4 + i;
                float cc = sigf(zf) * c_reg[ci] + sigf(zi) * tanhf_(zg);
                c_reg[ci] = cc;
                float hh = sigf(zo) * tanhf_(cc);
                unsigned short h16 = f2bf(hh);
                hv[i2][i] = h16;
                __hip_atomic_store(&hw[(long)(rbase + i2 * 16 + i) * 512 + colg], h16,
                                   __ATOMIC_RELAXED, __HIP_MEMORY_SCOPE_AGENT);
            }
        asm volatile("s_waitcnt vmcnt(0)" ::: "memory");
        if (l == 0) __hip_atomic_store(fme, (unsigned)(step + 2),
                                       __ATOMIC_RELAXED, __HIP_MEMORY_SCOPE_AGENT);
        // next step's Zx prefetch + Lout stores: fire-and-forget, off-path
        if (step < 63) zfetch(dir ? (62 - step) : (step + 1));
#pragma unroll
        for (int i2 = 0; i2 < 2; i2++)
#pragma unroll
            for (int i = 0; i < 4; i++)
                Lout[((long)t_eff * 256 + rbase + i2 * 16 + i) * 1024 + dir * 512 + colg] = hv[i2][i];
    }
}

// ---------------- alphas ----------------
__global__ __launch_bounds__(256) void k_alphas(const unsigned short* __restrict__ hbar,
                                                const unsigned short* __restrict__ ws2,
                                                float* __restrict__ att) {
    int w = threadIdx.x >> 6, l = threadIdx.x & 63;
    int mtile = blockIdx.x * 4 + w;
    f4 acc = {};
    const unsigned short* arow = hbar + (long)(mtile * 16 + (l & 15)) * 384 + (l >> 4) * 8;
    const unsigned short* brow = ws2 + (long)(l & 15) * 384 + (l >> 4) * 8;
    for (int ks = 0; ks < 12; ks++) {
        short8 a = *(const short8*)&arow[ks * 32];
        short8 b = *(const short8*)&brow[ks * 32];
        acc = __builtin_amdgcn_mfma_f32_16x16x32_bf16(a, b, acc, 0, 0, 0);
    }
    int r = l & 15;
#pragma unroll
    for (int i = 0; i < 4; i++) {
        int bt = mtile * 16 + (l >> 4) * 4 + i;
        int b = bt & 255, t = bt >> 8;
        att[((long)b * 16 + r) * 64 + t] = acc[i];
    }
}

// ---------------- sent: each thread owns one n-col, 8 r-accumulators ----------------
__global__ __launch_bounds__(256) void k_sent(const float* __restrict__ att,
                                              const unsigned short* __restrict__ L1,
                                              float* __restrict__ sent,
                                              unsigned short* __restrict__ sentb) {
    int b = blockIdx.x, n0 = blockIdx.y * 128;
    __shared__ float al[1024];
    for (int i = threadIdx.x; i < 1024; i += 256) al[i] = att[(long)b * 1024 + i];
    __syncthreads();
    int n = n0 + (threadIdx.x & 127);
    int rh = (threadIdx.x >> 7) * 8;
    float acc[8] = {};
    for (int t = 0; t < 64; t++) {
        float x = bf2f(L1[((long)t * 256 + b) * 1024 + n]);
#pragma unroll
        for (int r = 0; r < 8; r++) acc[r] += al[(rh + r) * 64 + t] * x;
    }
#pragma unroll
    for (int r = 0; r < 8; r++) {
        long o = ((long)b * 16 + rh + r) * 1024 + n;
        sent[o] = acc[r];
        sentb[o] = f2bf(acc[r]);
    }
}

// ---------------- dynamic routing ----------------
__global__ __launch_bounds__(256) void k_route(const float* __restrict__ votes,
                                               float* __restrict__ clog) {
    __shared__ float v[16384];
    __shared__ float logits[1024];
    __shared__ float route[1024];
    __shared__ float pre[1024];
    __shared__ float act[1024];
    __shared__ float cl[64];
    int b = blockIdx.x, tid = threadIdx.x;
    for (int i = tid; i < 4096; i += 256) ((f4*)v)[i] = ((const f4*)(votes + (long)b * 16384))[i];
    for (int i = tid; i < 1024; i += 256) logits[i] = 0.f;
    __syncthreads();
    for (int it = 0; it < 3; it++) {
        if (tid < 16) {
            float m = -1e30f;
            for (int s = 0; s < 64; s++) m = fmaxf(m, logits[tid * 64 + s]);
            float sum = 0.f;
            for (int s = 0; s < 64; s++) {
                float e = __expf(logits[tid * 64 + s] - m);
                route[tid * 64 + s] = e;
                sum += e;
            }
            float inv = 1.f / sum;
            for (int s = 0; s < 64; s++) route[tid * 64 + s] *= inv;
        }
        __syncthreads();
#pragma unroll
        for (int k = 0; k < 4; k++) {
            int p = k * 256 + tid;
            int s = p >> 4, a = p & 15;
            float acc = 0.f;
            for (int r = 0; r < 16; r++) acc += route[r * 64 + s] * v[(r * 64 + s) * 16 + a];
            pre[p] = acc;
        }
        __syncthreads();
        if (tid < 64) {
            float nsq = 0.f;
            for (int a = 0; a < 16; a++) nsq += pre[tid * 16 + a] * pre[tid * 16 + a];
            float norm = sqrtf(nsq);
            float sc = norm / (0.5f + nsq);
            for (int a = 0; a < 16; a++) act[tid * 16 + a] = pre[tid * 16 + a] * sc;
            cl[tid] = nsq / (0.5f + nsq);
        }
        __syncthreads();
#pragma unroll
        for (int k = 0; k < 4; k++) {
            int p = k * 256 + tid;
            int r = p >> 6, s = p & 63;
            float acc = 0.f;
            for (int a = 0; a < 16; a++) acc += v[(r * 64 + s) * 16 + a] * act[s * 16 + a];
            logits[p] += acc;
        }
        __syncthreads();
    }
    if (tid < 64) clog[(long)b * 64 + tid] = cl[tid];
}

// ---------------- host ----------------
extern "C" void kernel_launch(void* const* d_in, const int* in_sizes, int n_in,
                              void* d_out, int out_size, void* d_ws, size_t ws_size,
                              hipStream_t stream) {
    const int* tokens = (const int*)d_in[0];
    const float* embedding = (const float*)d_in[2];
    const float* Wih_l0f = (const float*)d_in[3];
    const float* Whh_l0f = (const float*)d_in[4];
    const float* b_l0f = (const float*)d_in[5];
    const float* Wih_l0b = (const float*)d_in[6];
    const float* Whh_l0b = (const float*)d_in[7];
    const float* b_l0b = (const float*)d_in[8];
    const float* Wih_l1f = (const float*)d_in[9];
    const float* Whh_l1f = (const float*)d_in[10];
    const float* b_l1f = (const float*)d_in[11];
    const float* Wih_l1b = (const float*)d_in[12];
    const float* Whh_l1b = (const float*)d_in[13];
    const float* b_l1b = (const float*)d_in[14];
    const float* ws1 = (const float*)d_in[15];
    const float* ws2 = (const float*)d_in[16];
    const float* caps_W = (const float*)d_in[17];
    float* out = (float*)d_out;

    char* ws = (char*)d_ws;
    size_t o = 0;
    unsigned short* Xb16 = (unsigned short*)(ws + o); o += (size_t)16384 * 320 * 2;
    unsigned short* ZxL = (unsigned short*)(ws + o); size_t zx_off = o; o += (size_t)2 * 16384 * 2048 * 2;
    unsigned short* L0 = (unsigned short*)(ws + o); o += (size_t)16384 * 1024 * 2;
    unsigned short* L1 = (unsigned short*)(ws + o); o += (size_t)16384 * 1024 * 2;
    unsigned short* Wl0b = (unsigned short*)(ws + o); o += (size_t)2 * 2048 * 320 * 2;
    unsigned short* Wl1b = (unsigned short*)(ws + o); o += (size_t)2 * 2048 * 1024 * 2;
    unsigned short* Wsh0 = (unsigned short*)(ws + o); o += (size_t)2 * 1048576 * 2;
    unsigned short* Wsh1 = (unsigned short*)(ws + o); o += (size_t)2 * 1048576 * 2;
    unsigned short* ws1b = (unsigned short*)(ws + o); o += (size_t)384 * 1024 * 2;
    unsigned short* ws2b = (unsigned short*)(ws + o); o += (size_t)16 * 384 * 2 + 192;
    float* biasc = (float*)(ws + o); o += (size_t)4 * 2048 * 4;
    unsigned* cnts = (unsigned*)(ws + o); o += 131072;  // 2 layers x 16384 u32 (64 KiB each) per-wave flags
    // UNION region: hsteps (34.1 MB, live only during the two k_lstm dispatches)
    // and capsT (33.5 MB, written after layer-1 lstm, read by the votes GEMM).
    const size_t HS_BYTES = (size_t)65 * 2 * 256 * 512 * 2;
    unsigned short* hsteps = (unsigned short*)(ws + o);
    unsigned short* capsT = (unsigned short*)(ws + o);
    o += HS_BYTES;
    // overlay region (inside ZxL, dead after layer-1 recurrence):
    unsigned short* hbarb = (unsigned short*)(ws + zx_off);
    float* att = (float*)(ws + zx_off + (size_t)16384 * 384 * 2);
    unsigned short* sentb = (unsigned short*)(ws + zx_off + (size_t)16384 * 384 * 2 + 1048576);
    float* votes = (float*)(ws + zx_off + (size_t)16384 * 384 * 2 + 1048576 + (size_t)256 * 16 * 1024 * 2);

    hipMemsetAsync(cnts, 0, 131072, stream);
    // sentinel-fill for layer-0 lstm (0x7F7F bf16 ~ 3.4e38, impossible h)
    hipMemsetAsync(hsteps, 0x7F, HS_BYTES, stream);

    k_embed<<<16384 * 320 / 256, 256, 0, stream>>>(tokens, embedding, Xb16);
    k_cvt_pad<<<(2048 * 320 + 255) / 256, 256, 0, stream>>>(Wih_l0f, Wl0b, 2048, 300, 2048, 320);
    k_cvt_pad<<<(2048 * 320 + 255) / 256, 256, 0, stream>>>(Wih_l0b, Wl0b + (size_t)2048 * 320, 2048, 300, 2048, 320);
    k_cvt_pad<<<(2048 * 1024 + 255) / 256, 256, 0, stream>>>(Wih_l1f, Wl1b, 2048, 1024, 2048, 1024);
    k_cvt_pad<<<(2048 * 1024 + 255) / 256, 256, 0, stream>>>(Wih_l1b, Wl1b + (size_t)2048 * 1024, 2048, 1024, 2048, 1024);
    k_cvt_pad<<<(384 * 1024 + 255) / 256, 256, 0, stream>>>(ws1, ws1b, 350, 1024, 384, 1024);
    k_cvt_pad<<<(16 * 384 + 255) / 256, 256, 0, stream>>>(ws2, ws2b, 16, 350, 16, 384);
    k_whh_shuf<<<4096, 256, 0, stream>>>(Whh_l0f, Wsh0);
    k_whh_shuf<<<4096, 256, 0, stream>>>(Whh_l0b, Wsh0 + 1048576);
    k_whh_shuf<<<4096, 256, 0, stream>>>(Whh_l1f, Wsh1);
    k_whh_shuf<<<4096, 256, 0, stream>>>(Whh_l1b, Wsh1 + 1048576);
    hipMemcpyAsync(biasc + 0, b_l0f, 2048 * 4, hipMemcpyDeviceToDevice, stream);
    hipMemcpyAsync(biasc + 2048, b_l0b, 2048 * 4, hipMemcpyDeviceToDevice, stream);
    hipMemcpyAsync(biasc + 4096, b_l1f, 2048 * 4, hipMemcpyDeviceToDevice, stream);
    hipMemcpyAsync(biasc + 6144, b_l1b, 2048 * 4, hipMemcpyDeviceToDevice, stream);

    hipFuncSetAttribute(reinterpret_cast<const void*>(k_lstm),
                        hipFuncAttributeMaxDynamicSharedMemorySize, 131072);

    k_gemm<1, 0><<<dim3(128, 16, 2), 256, 0, stream>>>(
        Xb16, Wl0b, ZxL, biasc, 320, 320, 2048,
        0L, (long)2048 * 320, (long)16384 * 2048, 2048L);
    k_lstm<<<128, 256, 131072, stream>>>(ZxL, Wsh0, hsteps, L0, cnts);
    // re-arm sentinel for layer-1 lstm (stream-ordered between the dispatches)
    hipMemsetAsync(hsteps, 0x7F, HS_BYTES, stream);
    k_gemm<1, 0><<<dim3(128, 16, 2), 256, 0, stream>>>(
        L0, Wl1b, ZxL, biasc + 4096, 1024, 1024, 2048,
        0L, (long)2048 * 1024, (long)16384 * 2048, 2048L);
    // layer-1 flag base: +16384 u32 = +64 KiB (one layer region, in-bounds)
    k_lstm<<<128, 256, 131072, stream>>>(ZxL, Wsh1, hsteps, L1, cnts + 16384);
    // capsT conversion AFTER the lstms: its buffer aliases hsteps (dead now)
    k_capsT<<<dim3(16, 32, 32), 256, 0, stream>>>(caps_W, capsT);
    k_gemm<1, 1><<<dim3(128, 3, 1), 256, 0, stream>>>(
        L1, ws1b, hbarb, nullptr, 1024, 1024, 384, 0L, 0L, 0L, 0L);
    k_alphas<<<256, 256, 0, stream>>>(hbarb, ws2b, att);
    k_sent<<<dim3(256, 8), 256, 0, stream>>>(att, L1, out, sentb);
    k_gemm<0, 0><<<dim3(2, 8, 16), 256, 0, stream>>>(
        sentb, capsT, votes, nullptr, 1024, 16384, 16384,
        1024L, 1048576L, 1024L, 0L);
    k_route<<<256, 256, 0, stream>>>(votes, out + (size_t)4194304);
}

// Round 10
// 1704.886 us; speedup vs baseline: 1.4451x; 1.1153x over previous
//
#include <hip/hip_runtime.h>
#include <stdint.h>

// Problem constants
#define PB 256
#define PT 64
#define PE 300
#define PH 512
#define PDA 350
#define PR 16
#define PS 64
#define PA 16

typedef __attribute__((ext_vector_type(8))) short short8;
typedef __attribute__((ext_vector_type(4))) float f4;
typedef unsigned long long u64;

__device__ __forceinline__ float bf2f(unsigned short u) {
    unsigned v = ((unsigned)u) << 16;
    return __builtin_bit_cast(float, v);
}
__device__ __forceinline__ unsigned short f2bf(float f) {
    unsigned u = __builtin_bit_cast(unsigned int, f);
    u = u + 0x7fffu + ((u >> 16) & 1u);
    return (unsigned short)(u >> 16);
}
__device__ __forceinline__ float sigf(float x) { return 1.f / (1.f + __expf(-x)); }
__device__ __forceinline__ float tanhf_(float x) { return 1.f - 2.f / (1.f + __expf(2.f * x)); }

// ---------------- converters ----------------

__global__ __launch_bounds__(256) void k_embed(const int* __restrict__ tokens,
                                               const float* __restrict__ emb,
                                               unsigned short* __restrict__ X) {
    int idx = blockIdx.x * 256 + threadIdx.x;
    if (idx >= 16384 * 320) return;
    int row = idx / 320, e = idx - row * 320;
    int t = row >> 8, b = row & 255;
    float v = 0.f;
    if (e < 300) v = emb[(long)tokens[b * 64 + t] * 300 + e];
    X[idx] = f2bf(v);
}

__global__ __launch_bounds__(256) void k_cvt_pad(const float* __restrict__ src,
                                                 unsigned short* __restrict__ dst,
                                                 int N, int K, int N2, int K2) {
    int idx = blockIdx.x * 256 + threadIdx.x;
    if (idx >= N2 * K2) return;
    int n = idx / K2, k = idx - n * K2;
    float v = (n < N && k < K) ? src[(long)n * K + k] : 0.f;
    dst[idx] = f2bf(v);
}

__global__ __launch_bounds__(256) void k_capsT(const float* __restrict__ src,
                                               unsigned short* __restrict__ dst) {
    __shared__ float tile[32][33];
    int r = blockIdx.x, kb = blockIdx.y * 32, nb = blockIdx.z * 32;
    int tx = threadIdx.x & 31, ty = threadIdx.x >> 5;
    for (int i = 0; i < 32; i += 8)
        tile[ty + i][tx] = src[((long)r << 20) + (long)(kb + ty + i) * 1024 + nb + tx];
    __syncthreads();
    for (int i = 0; i < 32; i += 8)
        dst[((long)r << 20) + (long)(nb + ty + i) * 1024 + kb + tx] = f2bf(tile[tx][ty + i]);
}

__global__ __launch_bounds__(256) void k_whh_shuf(const float* __restrict__ W,
                                                  unsigned short* __restrict__ dst) {
    int idx = blockIdx.x * 256 + threadIdx.x;
    int el = idx & 7, lane = (idx >> 3) & 63, ks = (idx >> 9) & 15, nt = (idx >> 13) & 7, hs = idx >> 16;
    int gcol = (nt >> 1) * 512 + hs * 32 + (nt & 1) * 16 + (lane & 15);
    int k = ks * 32 + (lane >> 4) * 8 + el;
    dst[idx] = f2bf(W[(long)gcol * 512 + k]);
}

// ---------------- generic bf16 MFMA GEMM ----------------
// Staging via __builtin_amdgcn_global_load_lds width=16 (async direct-to-LDS,
// no VGPR round-trip; the compiler never auto-emits this — measured +67% on
// this exact 128-tile structure in the guide ladder m93->m97). LDS dest is
// wave-uniform base &As[tI*512] + lane*16B (tI uniform per wave); the global
// source is per-lane (legal). The __syncthreads() after staging makes the
// compiler drain vmcnt before the barrier, so the async loads are complete
// before any ds_read.
template <int OUT_BF16, int TANH>
__global__ __launch_bounds__(256) void k_gemm(const unsigned short* __restrict__ A,
                                              const unsigned short* __restrict__ W,
                                              void* __restrict__ Cv,
                                              const float* __restrict__ bias,
                                              int K, int lda, int ldc,
                                              long aOffZ, long wOffZ, long cOffZ, long bOffZ) {
    A += blockIdx.z * aOffZ;
    W += blockIdx.z * wOffZ;
    if (bias) bias += blockIdx.z * bOffZ;
    const long cbase = blockIdx.z * cOffZ;
    const int m0 = blockIdx.x * 128, n0 = blockIdx.y * 128;
    __shared__ __align__(16) unsigned short As[4096], Bs[4096];
    const int w = threadIdx.x >> 6, l = threadIdx.x & 63;
    const int wm = w & 1, wn = w >> 1;
    const int fr = l & 15, fk = (l >> 4) * 8;
    f4 acc[4][4] = {};
    for (int k0 = 0; k0 < K; k0 += 32) {
        __syncthreads();
#pragma unroll
        for (int i = 0; i < 2; i++) {
            int tI = w + i * 4;
            const unsigned short* ga = A + (long)(m0 + tI * 16 + fr) * lda + k0 + fk;
            const unsigned short* gb = W + (long)(n0 + tI * 16 + fr) * K + k0 + fk;
            __builtin_amdgcn_global_load_lds(
                (const __attribute__((address_space(1))) void*)ga,
                (__attribute__((address_space(3))) void*)&As[tI * 512], 16, 0, 0);
            __builtin_amdgcn_global_load_lds(
                (const __attribute__((address_space(1))) void*)gb,
                (__attribute__((address_space(3))) void*)&Bs[tI * 512], 16, 0, 0);
        }
        __syncthreads();
        short8 av[4], bv[4];
#pragma unroll
        for (int mt = 0; mt < 4; mt++) av[mt] = *(short8*)&As[(wm * 4 + mt) * 512 + l * 8];
#pragma unroll
        for (int nt = 0; nt < 4; nt++) bv[nt] = *(short8*)&Bs[(wn * 4 + nt) * 512 + l * 8];
#pragma unroll
        for (int mt = 0; mt < 4; mt++)
#pragma unroll
            for (int nt = 0; nt < 4; nt++)
                acc[mt][nt] = __builtin_amdgcn_mfma_f32_16x16x32_bf16(av[mt], bv[nt], acc[mt][nt], 0, 0, 0);
    }
#pragma unroll
    for (int mt = 0; mt < 4; mt++) {
        int row = m0 + wm * 64 + mt * 16 + (l >> 4) * 4;
#pragma unroll
        for (int nt = 0; nt < 4; nt++) {
            int col = n0 + wn * 64 + nt * 16 + (l & 15);
            float bb = bias ? bias[col] : 0.f;
#pragma unroll
            for (int i = 0; i < 4; i++) {
                float v = acc[mt][nt][i] + bb;
                if (TANH) v = tanhf_(v);
                long off = cbase + (long)(row + i) * ldc + col;
                if (OUT_BF16)
                    ((unsigned short*)Cv)[off] = f2bf(v);
                else
                    ((float*)Cv)[off] = v;
            }
        }
    }
}

// ---------------- persistent bidirectional LSTM layer ----------------
// R2 protocol (HW-proven correct at 497us/dispatch; best of the 4 protocols
// measured across R2/R5/R8/R9):
//  writer: agent-scope relaxed h stores -> vmcnt(0) -> barrier -> tid0
//          relaxed atomicAdd counter
//  reader: tid0 relaxed poll -> barrier -> plain cached loads (L2-local
//          under the XCD-colocating swizzle; the us-scale counter+barrier
//          slack is what makes cached reads safe — leaner per-wave flags
//          (R8) exposed an IF flag-vs-data race, and bypass reads (R5/R9)
//          burn IF bandwidth on the group's 32x read amplification).
// Gate math fully in-lane (MFMA C layout: all 4 gates of a cell live in the
// same lane across acc[i2][s][i]); no LDS transpose; 2 barriers/step; Lout
// stores deferred past the signal (drained by the next step's vmcnt(0)).
__global__ __launch_bounds__(256, 1) void k_lstm(const unsigned short* __restrict__ Zx,
                                                 const unsigned short* __restrict__ Wshuf,
                                                 unsigned short* __restrict__ hsteps,
                                                 unsigned short* __restrict__ Lout,
                                                 unsigned* __restrict__ cnt) {
    extern __shared__ char smem[];
    unsigned short* Wl = (unsigned short*)smem;        // 128 KB, resident all 64 steps
    const int bid = blockIdx.x;
    // XCD-colocating swizzle: group g = bid&7 -> blocks {g, g+8, ...} all
    // congruent mod 8 -> same XCD under round-robin dispatch (L2-local h).
    const int g = bid & 7, hs = bid >> 3;
    const int dir = g >> 2, bg = g & 3;
    const int tid = threadIdx.x;
    const int l = tid & 63;
    const int w = tid >> 6;
    const int mt2 = w & 1, hc2 = w >> 1;

    // Whh slice into LDS (resident for all 64 steps)
    {
        const short8* src = (const short8*)(Wshuf + ((long)(dir * 16 + hs) << 16));
        short8* dst = (short8*)Wl;
        for (int i = tid; i < 8192; i += 256) dst[i] = src[i];
    }
    // zero step-0 h (agent-scope so cross-XCD readers see it)
    {
        unsigned short* hz = hsteps + (long)dir * (256 * 512);
        for (int i = tid; i < 1024; i += 256) {
            int r = i >> 4, c2 = i & 15;
            __hip_atomic_store((unsigned*)&hz[(bg * 64 + r) * 512 + hs * 32 + c2 * 2], 0u,
                               __ATOMIC_RELAXED, __HIP_MEMORY_SCOPE_AGENT);
        }
    }
    unsigned* myc = cnt + g * 32;  // 128-B spacing: no line sharing
    asm volatile("s_waitcnt vmcnt(0)" ::: "memory");
    __syncthreads();
    if (tid == 0) __hip_atomic_fetch_add(myc, 1u, __ATOMIC_RELAXED, __HIP_MEMORY_SCOPE_AGENT);

    float c_reg[8];
#pragma unroll
    for (int i = 0; i < 8; i++) c_reg[i] = 0.f;

    // this lane's fixed output cells: rows rbase+i2*16+i, col colg
    const int colg = hs * 32 + hc2 * 16 + (l & 15);
    const int rbase = bg * 64 + mt2 * 32 + (l >> 4) * 4;

    for (int step = 0; step < 64; step++) {
        const int t_eff = dir ? (63 - step) : step;
        const unsigned short* zbase = Zx + ((long)dir * 16384 + (long)t_eff * 256) * 2048;

        // prefetch Zx gates for this lane's 8 cells (independent of h -> pre-poll)
        unsigned short zpre[2][4][4];
#pragma unroll
        for (int i2 = 0; i2 < 2; i2++)
#pragma unroll
            for (int i = 0; i < 4; i++) {
                const unsigned short* zrow = zbase + (long)(rbase + i2 * 16 + i) * 2048 + colg;
#pragma unroll
                for (int s = 0; s < 4; s++) zpre[i2][i][s] = zrow[s * 512];
            }

        if (tid == 0) {
            unsigned target = 16u * (unsigned)(step + 1);
            while (__hip_atomic_load(myc, __ATOMIC_RELAXED, __HIP_MEMORY_SCOPE_AGENT) < target) {}
        }
        __syncthreads();

        // GEMM: h(rows of this wave) @ WhhT(slice); cached h loads (L2-local),
        // register-staged ahead of the MFMA stream.
        f4 acc[2][4] = {};
        const unsigned short* hbp = hsteps + ((long)step * 2 + dir) * (256 * 512);
        const unsigned short* pa0 = hbp + (bg * 64 + (mt2 * 2 + 0) * 16 + (l & 15)) * 512 + (l >> 4) * 8;
        const unsigned short* pa1 = hbp + (bg * 64 + (mt2 * 2 + 1) * 16 + (l & 15)) * 512 + (l >> 4) * 8;
        short8 a0r[16], a1r[16];
#pragma unroll
        for (int ks = 0; ks < 16; ks++) {
            a0r[ks] = *(const short8*)(pa0 + ks * 32);
            a1r[ks] = *(const short8*)(pa1 + ks * 32);
        }
#pragma unroll
        for (int ks = 0; ks < 16; ks++) {
#pragma unroll
            for (int s = 0; s < 4; s++) {
                int nt = s * 2 + hc2;
                short8 b = *(short8*)&Wl[((nt * 16 + ks) * 64 + l) * 8];
                acc[0][s] = __builtin_amdgcn_mfma_f32_16x16x32_bf16(a0r[ks], b, acc[0][s], 0, 0, 0);
                acc[1][s] = __builtin_amdgcn_mfma_f32_16x16x32_bf16(a1r[ks], b, acc[1][s], 0, 0, 0);
            }
        }

        // in-lane gate math: all 4 gates of cell (i2,i) are acc[i2][0..3][i]
        unsigned short* hw = hsteps + ((long)(step + 1) * 2 + dir) * (256 * 512);
        unsigned short hv[2][4];
#pragma unroll
        for (int i2 = 0; i2 < 2; i2++)
#pragma unroll
            for (int i = 0; i < 4; i++) {
                float zi = acc[i2][0][i] + bf2f(zpre[i2][i][0]);
                float zf = acc[i2][1][i] + bf2f(zpre[i2][i][1]);
                float zg = acc[i2][2][i] + bf2f(zpre[i2][i][2]);
                float zo = acc[i2][3][i] + bf2f(zpre[i2][i][3]);
                int ci = i2 * 4 + i;
                float cc = sigf(zf) * c_reg[ci] + sigf(zi) * tanhf_(zg);
                c_reg[ci] = cc;
                float hh = sigf(zo) * tanhf_(cc);
                unsigned short h16 = f2bf(hh);
                hv[i2][i] = h16;
                __hip_atomic_store(&hw[(long)(rbase + i2 * 16 + i) * 512 + colg], h16,
                                   __ATOMIC_RELAXED, __HIP_MEMORY_SCOPE_AGENT);
            }
        asm volatile("s_waitcnt vmcnt(0)" ::: "memory");
        __syncthreads();
        if (tid == 0) __hip_atomic_fetch_add(myc, 1u, __ATOMIC_RELAXED, __HIP_MEMORY_SCOPE_AGENT);
        // Lout stores AFTER the signal: off the recurrence critical path,
        // drained by the next step's vmcnt(0) (or kernel end).
#pragma unroll
        for (int i2 = 0; i2 < 2; i2++)
#pragma unroll
            for (int i = 0; i < 4; i++)
                Lout[((long)t_eff * 256 + rbase + i2 * 16 + i) * 1024 + dir * 512 + colg] = hv[i2][i];
    }
}

// ---------------- alphas ----------------
__global__ __launch_bounds__(256) void k_alphas(const unsigned short* __restrict__ hbar,
                                                const unsigned short* __restrict__ ws2,
                                                float* __restrict__ att) {
    int w = threadIdx.x >> 6, l = threadIdx.x & 63;
    int mtile = blockIdx.x * 4 + w;
    f4 acc = {};
    const unsigned short* arow = hbar + (long)(mtile * 16 + (l & 15)) * 384 + (l >> 4) * 8;
    const unsigned short* brow = ws2 + (long)(l & 15) * 384 + (l >> 4) * 8;
    for (int ks = 0; ks < 12; ks++) {
        short8 a = *(const short8*)&arow[ks * 32];
        short8 b = *(const short8*)&brow[ks * 32];
        acc = __builtin_amdgcn_mfma_f32_16x16x32_bf16(a, b, acc, 0, 0, 0);
    }
    int r = l & 15;
#pragma unroll
    for (int i = 0; i < 4; i++) {
        int bt = mtile * 16 + (l >> 4) * 4 + i;
        int b = bt & 255, t = bt >> 8;
        att[((long)b * 16 + r) * 64 + t] = acc[i];
    }
}

// ---------------- sent: each thread owns one n-col, 8 r-accumulators ----------------
__global__ __launch_bounds__(256) void k_sent(const float* __restrict__ att,
                                              const unsigned short* __restrict__ L1,
                                              float* __restrict__ sent,
                                              unsigned short* __restrict__ sentb) {
    int b = blockIdx.x, n0 = blockIdx.y * 128;
    __shared__ float al[1024];
    for (int i = threadIdx.x; i < 1024; i += 256) al[i] = att[(long)b * 1024 + i];
    __syncthreads();
    int n = n0 + (threadIdx.x & 127);
    int rh = (threadIdx.x >> 7) * 8;
    float acc[8] = {};
    for (int t = 0; t < 64; t++) {
        float x = bf2f(L1[((long)t * 256 + b) * 1024 + n]);
#pragma unroll
        for (int r = 0; r < 8; r++) acc[r] += al[(rh + r) * 64 + t] * x;
    }
#pragma unroll
    for (int r = 0; r < 8; r++) {
        long o = ((long)b * 16 + rh + r) * 1024 + n;
        sent[o] = acc[r];
        sentb[o] = f2bf(acc[r]);
    }
}

// ---------------- dynamic routing ----------------
__global__ __launch_bounds__(256) void k_route(const float* __restrict__ votes,
                                               float* __restrict__ clog) {
    __shared__ float v[16384];
    __shared__ float logits[1024];
    __shared__ float route[1024];
    __shared__ float pre[1024];
    __shared__ float act[1024];
    __shared__ float cl[64];
    int b = blockIdx.x, tid = threadIdx.x;
    for (int i = tid; i < 4096; i += 256) ((f4*)v)[i] = ((const f4*)(votes + (long)b * 16384))[i];
    for (int i = tid; i < 1024; i += 256) logits[i] = 0.f;
    __syncthreads();
    for (int it = 0; it < 3; it++) {
        if (tid < 16) {
            float m = -1e30f;
            for (int s = 0; s < 64; s++) m = fmaxf(m, logits[tid * 64 + s]);
            float sum = 0.f;
            for (int s = 0; s < 64; s++) {
                float e = __expf(logits[tid * 64 + s] - m);
                route[tid * 64 + s] = e;
                sum += e;
            }
            float inv = 1.f / sum;
            for (int s = 0; s < 64; s++) route[tid * 64 + s] *= inv;
        }
        __syncthreads();
#pragma unroll
        for (int k = 0; k < 4; k++) {
            int p = k * 256 + tid;
            int s = p >> 4, a = p & 15;
            float acc = 0.f;
            for (int r = 0; r < 16; r++) acc += route[r * 64 + s] * v[(r * 64 + s) * 16 + a];
            pre[p] = acc;
        }
        __syncthreads();
        if (tid < 64) {
            float nsq = 0.f;
            for (int a = 0; a < 16; a++) nsq += pre[tid * 16 + a] * pre[tid * 16 + a];
            float norm = sqrtf(nsq);
            float sc = norm / (0.5f + nsq);
            for (int a = 0; a < 16; a++) act[tid * 16 + a] = pre[tid * 16 + a] * sc;
            cl[tid] = nsq / (0.5f + nsq);
        }
        __syncthreads();
#pragma unroll
        for (int k = 0; k < 4; k++) {
            int p = k * 256 + tid;
            int r = p >> 6, s = p & 63;
            float acc = 0.f;
            for (int a = 0; a < 16; a++) acc += v[(r * 64 + s) * 16 + a] * act[s * 16 + a];
            logits[p] += acc;
        }
        __syncthreads();
    }
    if (tid < 64) clog[(long)b * 64 + tid] = cl[tid];
}

// ---------------- host ----------------
extern "C" void kernel_launch(void* const* d_in, const int* in_sizes, int n_in,
                              void* d_out, int out_size, void* d_ws, size_t ws_size,
                              hipStream_t stream) {
    const int* tokens = (const int*)d_in[0];
    const float* embedding = (const float*)d_in[2];
    const float* Wih_l0f = (const float*)d_in[3];
    const float* Whh_l0f = (const float*)d_in[4];
    const float* b_l0f = (const float*)d_in[5];
    const float* Wih_l0b = (const float*)d_in[6];
    const float* Whh_l0b = (const float*)d_in[7];
    const float* b_l0b = (const float*)d_in[8];
    const float* Wih_l1f = (const float*)d_in[9];
    const float* Whh_l1f = (const float*)d_in[10];
    const float* b_l1f = (const float*)d_in[11];
    const float* Wih_l1b = (const float*)d_in[12];
    const float* Whh_l1b = (const float*)d_in[13];
    const float* b_l1b = (const float*)d_in[14];
    const float* ws1 = (const float*)d_in[15];
    const float* ws2 = (const float*)d_in[16];
    const float* caps_W = (const float*)d_in[17];
    float* out = (float*)d_out;

    char* ws = (char*)d_ws;
    size_t o = 0;
    unsigned short* Xb16 = (unsigned short*)(ws + o); o += (size_t)16384 * 320 * 2;
    unsigned short* ZxL = (unsigned short*)(ws + o); size_t zx_off = o; o += (size_t)2 * 16384 * 2048 * 2;
    unsigned short* L0 = (unsigned short*)(ws + o); o += (size_t)16384 * 1024 * 2;
    unsigned short* L1 = (unsigned short*)(ws + o); o += (size_t)16384 * 1024 * 2;
    unsigned short* Wl0b = (unsigned short*)(ws + o); o += (size_t)2 * 2048 * 320 * 2;
    unsigned short* Wl1b = (unsigned short*)(ws + o); o += (size_t)2 * 2048 * 1024 * 2;
    unsigned short* Wsh0 = (unsigned short*)(ws + o); o += (size_t)2 * 1048576 * 2;
    unsigned short* Wsh1 = (unsigned short*)(ws + o); o += (size_t)2 * 1048576 * 2;
    unsigned short* ws1b = (unsigned short*)(ws + o); o += (size_t)384 * 1024 * 2;
    unsigned short* ws2b = (unsigned short*)(ws + o); o += (size_t)16 * 384 * 2 + 192;
    float* biasc = (float*)(ws + o); o += (size_t)4 * 2048 * 4;
    unsigned* cnts = (unsigned*)(ws + o); o += 4096;  // 2 layers x 8 groups x 128B
    // UNION region: hsteps (34.1 MB, live only during the two k_lstm dispatches)
    // and capsT (33.5 MB, written after layer-1 lstm, read by the votes GEMM).
    unsigned short* hsteps = (unsigned short*)(ws + o);
    unsigned short* capsT = (unsigned short*)(ws + o);
    o += (size_t)65 * 2 * 256 * 512 * 2;
    // overlay region (inside ZxL, dead after layer-1 recurrence):
    unsigned short* hbarb = (unsigned short*)(ws + zx_off);
    float* att = (float*)(ws + zx_off + (size_t)16384 * 384 * 2);
    unsigned short* sentb = (unsigned short*)(ws + zx_off + (size_t)16384 * 384 * 2 + 1048576);
    float* votes = (float*)(ws + zx_off + (size_t)16384 * 384 * 2 + 1048576 + (size_t)256 * 16 * 1024 * 2);

    hipMemsetAsync(cnts, 0, 4096, stream);

    k_embed<<<16384 * 320 / 256, 256, 0, stream>>>(tokens, embedding, Xb16);
    k_cvt_pad<<<(2048 * 320 + 255) / 256, 256, 0, stream>>>(Wih_l0f, Wl0b, 2048, 300, 2048, 320);
    k_cvt_pad<<<(2048 * 320 + 255) / 256, 256, 0, stream>>>(Wih_l0b, Wl0b + (size_t)2048 * 320, 2048, 300, 2048, 320);
    k_cvt_pad<<<(2048 * 1024 + 255) / 256, 256, 0, stream>>>(Wih_l1f, Wl1b, 2048, 1024, 2048, 1024);
    k_cvt_pad<<<(2048 * 1024 + 255) / 256, 256, 0, stream>>>(Wih_l1b, Wl1b + (size_t)2048 * 1024, 2048, 1024, 2048, 1024);
    k_cvt_pad<<<(384 * 1024 + 255) / 256, 256, 0, stream>>>(ws1, ws1b, 350, 1024, 384, 1024);
    k_cvt_pad<<<(16 * 384 + 255) / 256, 256, 0, stream>>>(ws2, ws2b, 16, 350, 16, 384);
    k_whh_shuf<<<4096, 256, 0, stream>>>(Whh_l0f, Wsh0);
    k_whh_shuf<<<4096, 256, 0, stream>>>(Whh_l0b, Wsh0 + 1048576);
    k_whh_shuf<<<4096, 256, 0, stream>>>(Whh_l1f, Wsh1);
    k_whh_shuf<<<4096, 256, 0, stream>>>(Whh_l1b, Wsh1 + 1048576);
    hipMemcpyAsync(biasc + 0, b_l0f, 2048 * 4, hipMemcpyDeviceToDevice, stream);
    hipMemcpyAsync(biasc + 2048, b_l0b, 2048 * 4, hipMemcpyDeviceToDevice, stream);
    hipMemcpyAsync(biasc + 4096, b_l1f, 2048 * 4, hipMemcpyDeviceToDevice, stream);
    hipMemcpyAsync(biasc + 6144, b_l1b, 2048 * 4, hipMemcpyDeviceToDevice, stream);

    hipFuncSetAttribute(reinterpret_cast<const void*>(k_lstm),
                        hipFuncAttributeMaxDynamicSharedMemorySize, 131072);

    k_gemm<1, 0><<<dim3(128, 16, 2), 256, 0, stream>>>(
        Xb16, Wl0b, ZxL, biasc, 320, 320, 2048,
        0L, (long)2048 * 320, (long)16384 * 2048, 2048L);
    k_lstm<<<128, 256, 131072, stream>>>(ZxL, Wsh0, hsteps, L0, cnts);
    k_gemm<1, 0><<<dim3(128, 16, 2), 256, 0, stream>>>(
        L0, Wl1b, ZxL, biasc + 4096, 1024, 1024, 2048,
        0L, (long)2048 * 1024, (long)16384 * 2048, 2048L);
    k_lstm<<<128, 256, 131072, stream>>>(ZxL, Wsh1, hsteps, L1, cnts + 256);
    // capsT conversion AFTER the lstms: its buffer aliases hsteps (dead now)
    k_capsT<<<dim3(16, 32, 32), 256, 0, stream>>>(caps_W, capsT);
    k_gemm<1, 1><<<dim3(128, 3, 1), 256, 0, stream>>>(
        L1, ws1b, hbarb, nullptr, 1024, 1024, 384, 0L, 0L, 0L, 0L);
    k_alphas<<<256, 256, 0, stream>>>(hbarb, ws2b, att);
    k_sent<<<dim3(256, 8), 256, 0, stream>>>(att, L1, out, sentb);
    k_gemm<0, 0><<<dim3(2, 8, 16), 256, 0, stream>>>(
        sentb, capsT, votes, nullptr, 1024, 16384, 16384,
        1024L, 1048576L, 1024L, 0L);
    k_route<<<256, 256, 0, stream>>>(votes, out + (size_t)4194304);
}